// Round 1
// baseline (125.830 us; speedup 1.0000x reference)
//
#include <hip/hip_runtime.h>

// Problem constants (fixed by setup_inputs):
// B=8192, F=256, N=128, D=6, U=16, C=2^D=64
#define B_SZ   8192
#define F_SZ   256
#define N_TR   128
#define U_SZ   16

// K2 tiling
#define BM     128      // rows (b) per block
#define NT     8        // trees per block
#define BN     48       // NT*6 columns
#define KC     64       // K-chunk
#define XS_LD  132      // padded LDS stride for xs (bank spread, keeps 16B align)

// ws layout in floats:
//   Wp    [256][768]        @ 0         (196608)
//   bias  [768]             @ 196608    (768)
//   respT [128][64][16]     @ 197376    (131072)
//   part  [16][8192][16]    @ 328448    (2097152)
// total 2425600 floats = 9,702,400 bytes
#define WP_OFF    0
#define BIAS_OFF  196608
#define RESPT_OFF 197376
#define PART_OFF  328448

// ---------------------------------------------------------------- K0: response transpose
__global__ __launch_bounds__(256) void k0_respT(const float* __restrict__ resp,
                                                float* __restrict__ respT) {
    int idx = blockIdx.x * 256 + threadIdx.x;   // 131072 elements
    int n = idx >> 10;          // tree
    int c = (idx >> 4) & 63;    // leaf
    int u = idx & 15;           // unit
    // respT[n][c][u] = resp[n][u][c]
    respT[idx] = resp[n * 1024 + u * 64 + c];
}

// ---------------------------------------------------------------- K1: sparsemax + fold
__global__ __launch_bounds__(256) void k1_sparsemax(const float* __restrict__ fsl,
                                                    const float* __restrict__ thr,
                                                    const float* __restrict__ logt,
                                                    float* __restrict__ Wp,
                                                    float* __restrict__ bias) {
    int t = blockIdx.x * 256 + threadIdx.x;     // 32768 = 256 features * 128 trees
    int i = t >> 7;     // feature
    int n = t & 127;    // tree
    const float* zp = fsl + (i * 128 + n) * 6;

    float z[6], zs[6];
    #pragma unroll
    for (int d = 0; d < 6; ++d) { z[d] = zp[d]; zs[d] = z[d]; }

    // selection sort, descending (6 elements, 15 min/max pairs)
    #pragma unroll
    for (int a = 0; a < 5; ++a) {
        #pragma unroll
        for (int b = a + 1; b < 6; ++b) {
            float hi = fmaxf(zs[a], zs[b]);
            float lo = fminf(zs[a], zs[b]);
            zs[a] = hi; zs[b] = lo;
        }
    }

    // support set: 1 + k*zs_k > cumsum_k  (prefix property -> take last true)
    float cs = 0.f, csel = 0.f;
    int   km = 1;
    #pragma unroll
    for (int k = 0; k < 6; ++k) {
        cs += zs[k];
        if (1.0f + (float)(k + 1) * zs[k] > cs) { km = k + 1; csel = cs; }
    }
    float tau = (csel - 1.0f) / (float)km;

    #pragma unroll
    for (int d = 0; d < 6; ++d) {
        float invT = expf(-logt[n * 6 + d]);
        float sel  = fmaxf(z[d] - tau, 0.0f);
        // gate1 = clamp( fv*0.5*invT + (0.5 - 0.5*invT*thr), 0, 1 )
        Wp[i * 768 + n * 6 + d] = sel * 0.5f * invT;
        if (i == 0) {
            bias[n * 6 + d] = 0.5f - 0.5f * invT * thr[n * 6 + d];
        }
    }
}

// ---------------------------------------------------------------- K2: fused GEMM + trees
__global__ __launch_bounds__(256) void k2_fused(const float* __restrict__ x,
                                                const float* __restrict__ Wp,
                                                const float* __restrict__ bias,
                                                const float* __restrict__ respT,
                                                float* __restrict__ part) {
    // region 0..11519: phase1 xs[64][132] (8448) + wl[64][48] (3072)
    // aliased after GEMM as fv_l[128][68] (8704), then out_l (6144) after phase4
    __shared__ float smem[11520];
    float* xs = smem;
    float* wl = smem + KC * XS_LD;   // +8448

    int tid = threadIdx.x;
    int rt  = blockIdx.x;    // row tile  (64)
    int nt  = blockIdx.y;    // tree tile (16)
    int tc  = tid & 15;      // col-thread: 3 cols each
    int tr  = tid >> 4;      // row-thread: 8 rows each

    float acc[8][3];
    #pragma unroll
    for (int a = 0; a < 8; ++a)
        #pragma unroll
        for (int b = 0; b < 3; ++b) acc[a][b] = 0.f;

    const float* xbase = x + (size_t)(rt * BM) * 256;

    // ---------------- phase 1: GEMM fv[128][48] = X[128][256] * Wp[256][48-slice]
    for (int kc = 0; kc < 4; ++kc) {
        // stage xs (transposed: xs[k][r]), 2048 float4 loads
        #pragma unroll
        for (int it = 0; it < 8; ++it) {
            int idx = it * 256 + tid;
            int r   = idx >> 4;
            int k4  = (idx & 15) * 4;
            const float4 v = *(const float4*)(xbase + r * 256 + kc * 64 + k4);
            xs[(k4 + 0) * XS_LD + r] = v.x;
            xs[(k4 + 1) * XS_LD + r] = v.y;
            xs[(k4 + 2) * XS_LD + r] = v.z;
            xs[(k4 + 3) * XS_LD + r] = v.w;
        }
        // stage wl[k][48], 768 float4 loads
        #pragma unroll
        for (int it = 0; it < 3; ++it) {
            int idx = it * 256 + tid;
            int k   = idx / 12;
            int c4  = (idx % 12) * 4;
            const float4 v = *(const float4*)(Wp + (size_t)(kc * 64 + k) * 768 + nt * BN + c4);
            *(float4*)(wl + k * BN + c4) = v;
        }
        __syncthreads();

        #pragma unroll 8
        for (int k = 0; k < KC; ++k) {
            float a0[8];
            const float4 va = *(const float4*)(xs + k * XS_LD + tr * 8);
            const float4 vb = *(const float4*)(xs + k * XS_LD + tr * 8 + 4);
            a0[0] = va.x; a0[1] = va.y; a0[2] = va.z; a0[3] = va.w;
            a0[4] = vb.x; a0[5] = vb.y; a0[6] = vb.z; a0[7] = vb.w;
            float w0 = wl[k * BN + tc * 3 + 0];
            float w1 = wl[k * BN + tc * 3 + 1];
            float w2 = wl[k * BN + tc * 3 + 2];
            #pragma unroll
            for (int j = 0; j < 8; ++j) {
                acc[j][0] = fmaf(a0[j], w0, acc[j][0]);
                acc[j][1] = fmaf(a0[j], w1, acc[j][1]);
                acc[j][2] = fmaf(a0[j], w2, acc[j][2]);
            }
        }
        __syncthreads();
    }

    // ---------------- phase 2: gates -> fv_l[r][nl*8+d]  (aliases xs/wl, now dead)
    #pragma unroll
    for (int jc = 0; jc < 3; ++jc) {
        int col = tc * 3 + jc;     // 0..47
        int nl  = col / 6;
        int d   = col % 6;
        float bv = bias[nt * BN + col];
        #pragma unroll
        for (int jr = 0; jr < 8; ++jr) {
            int r = tr * 8 + jr;
            float s = acc[jr][jc] + bv;
            float g = fminf(fmaxf(s, 0.f), 1.f);
            smem[r * 68 + nl * 8 + d] = g;
        }
    }
    __syncthreads();

    // ---------------- phase 4: leaf probs + response contraction
    int r2 = tid & 63;
    int q  = tid >> 6;      // 0..3, two local trees each
    float au0[16], au1[16];
    #pragma unroll
    for (int u = 0; u < 16; ++u) { au0[u] = 0.f; au1[u] = 0.f; }

    for (int e = 0; e < 2; ++e) {
        int nl = q * 2 + e;
        const float* f0 = smem + r2 * 68 + nl * 8;
        const float* f1 = smem + (r2 + 64) * 68 + nl * 8;
        float g0[6], g1[6];
        #pragma unroll
        for (int d = 0; d < 6; ++d) { g0[d] = f0[d]; g1[d] = f1[d]; }

        // split leaf products: pa over depth 0..2 (bits 0..2), pb over depth 3..5
        float pa0[8], pb0[8], pa1[8], pb1[8];
        #pragma unroll
        for (int j = 0; j < 8; ++j) {
            float a0 = (j & 1) ? (1.f - g0[0]) : g0[0];
            float a1 = (j & 2) ? (1.f - g0[1]) : g0[1];
            float a2 = (j & 4) ? (1.f - g0[2]) : g0[2];
            pa0[j] = a0 * a1 * a2;
            float b0 = (j & 1) ? (1.f - g0[3]) : g0[3];
            float b1 = (j & 2) ? (1.f - g0[4]) : g0[4];
            float b2 = (j & 4) ? (1.f - g0[5]) : g0[5];
            pb0[j] = b0 * b1 * b2;
            float c0 = (j & 1) ? (1.f - g1[0]) : g1[0];
            float c1 = (j & 2) ? (1.f - g1[1]) : g1[1];
            float c2 = (j & 4) ? (1.f - g1[2]) : g1[2];
            pa1[j] = c0 * c1 * c2;
            float d0 = (j & 1) ? (1.f - g1[3]) : g1[3];
            float d1 = (j & 2) ? (1.f - g1[4]) : g1[4];
            float d2 = (j & 4) ? (1.f - g1[5]) : g1[5];
            pb1[j] = d0 * d1 * d2;
        }

        const float* rp = respT + (size_t)(nt * 8 + nl) * 1024;   // [c][u]
        #pragma unroll
        for (int c = 0; c < 64; ++c) {
            float p0 = pa0[c & 7] * pb0[c >> 3];
            float p1 = pa1[c & 7] * pb1[c >> 3];
            float rv[16];
            *(float4*)(rv + 0)  = *(const float4*)(rp + c * 16 + 0);
            *(float4*)(rv + 4)  = *(const float4*)(rp + c * 16 + 4);
            *(float4*)(rv + 8)  = *(const float4*)(rp + c * 16 + 8);
            *(float4*)(rv + 12) = *(const float4*)(rp + c * 16 + 12);
            #pragma unroll
            for (int u = 0; u < 16; ++u) {
                au0[u] = fmaf(p0, rv[u], au0[u]);
                au1[u] = fmaf(p1, rv[u], au1[u]);
            }
        }
    }
    __syncthreads();   // fv_l dead, reuse smem for cross-q reduction

    if (q > 0) {
        float* ol = smem + ((q - 1) * 64 + r2) * 32;
        #pragma unroll
        for (int u = 0; u < 16; ++u) { ol[u] = au0[u]; ol[16 + u] = au1[u]; }
    }
    __syncthreads();
    if (q == 0) {
        #pragma unroll
        for (int qq = 0; qq < 3; ++qq) {
            const float* ol = smem + (qq * 64 + r2) * 32;
            #pragma unroll
            for (int u = 0; u < 16; ++u) { au0[u] += ol[u]; au1[u] += ol[16 + u]; }
        }
        float* p0p = part + (size_t)nt * (B_SZ * 16) + (size_t)(rt * BM + r2) * 16;
        float* p1p = p0p + 64 * 16;
        #pragma unroll
        for (int u = 0; u < 16; u += 4) {
            float4 v0; v0.x = au0[u]; v0.y = au0[u+1]; v0.z = au0[u+2]; v0.w = au0[u+3];
            *(float4*)(p0p + u) = v0;
            float4 v1; v1.x = au1[u]; v1.y = au1[u+1]; v1.z = au1[u+2]; v1.w = au1[u+3];
            *(float4*)(p1p + u) = v1;
        }
    }
}

// ---------------------------------------------------------------- K3: n-tile reduction
__global__ __launch_bounds__(256) void k3_reduce(const float* __restrict__ part,
                                                 float* __restrict__ out) {
    int idx = blockIdx.x * 256 + threadIdx.x;   // 131072
    float s = 0.f;
    #pragma unroll
    for (int t = 0; t < 16; ++t) s += part[(size_t)t * 131072 + idx];
    out[idx] = s * (1.0f / 128.0f);
}

// ---------------------------------------------------------------- launch
extern "C" void kernel_launch(void* const* d_in, const int* in_sizes, int n_in,
                              void* d_out, int out_size, void* d_ws, size_t ws_size,
                              hipStream_t stream) {
    (void)in_sizes; (void)n_in; (void)out_size; (void)ws_size;
    const float* x    = (const float*)d_in[0];
    const float* fsl  = (const float*)d_in[1];
    const float* thr  = (const float*)d_in[2];
    const float* logt = (const float*)d_in[3];
    const float* resp = (const float*)d_in[4];
    float* ws    = (float*)d_ws;
    float* Wp    = ws + WP_OFF;
    float* bias  = ws + BIAS_OFF;
    float* respT = ws + RESPT_OFF;
    float* part  = ws + PART_OFF;
    float* out   = (float*)d_out;

    k0_respT    <<<512, 256, 0, stream>>>(resp, respT);
    k1_sparsemax<<<128, 256, 0, stream>>>(fsl, thr, logt, Wp, bias);
    k2_fused    <<<dim3(64, 16), 256, 0, stream>>>(x, Wp, bias, respT, part);
    k3_reduce   <<<512, 256, 0, stream>>>(part, out);
}

// Round 2
// 32.814 us; speedup vs baseline: 3.8346x; 3.8346x over previous
//
#include <hip/hip_runtime.h>
#include <hip/hip_bf16.h>

// B=8192, F=256(K), N=128 trees, D=6, U=16, C=64
// cols = n*6+d  (768 total)

typedef float f32x4 __attribute__((ext_vector_type(4)));
typedef short s16x8 __attribute__((ext_vector_type(8)));
typedef unsigned int u32;

// ws layout (bytes):
//   WpF   bf16 [48ct][8kt][64lane][8]  @ 0        393216 B
//   respF bf16 [128n][2kt][64lane][8]  @ 393216   262144 B
//   bias  f32  [768]                   @ 655360     3072 B
#define WPF_OFF   0
#define RESPF_OFF 393216
#define BIAS_OFF  655360

#define GLD    776            // gates LDS row stride (bf16 elems), 768+8 pad
#define GLROWB (GLD * 2)      // 1552 bytes

__device__ inline unsigned short bf16r(float f) {
    union { __hip_bfloat16 b; unsigned short s; } u;
    u.b = __float2bfloat16(f);
    return u.s;
}

__device__ inline u32 pack2(float a, float b) {
    union { __hip_bfloat162 h; u32 u; } p;
    p.h = __float22bfloat162_rn(make_float2(a, b));
    return p.u;
}

union frag_u { u32 w[4]; s16x8 v; int4 i4; };

__device__ inline f32x4 mfma_bf16(s16x8 a, s16x8 b, f32x4 c) {
    return __builtin_amdgcn_mfma_f32_16x16x32_bf16(a, b, c, 0, 0, 0);
}

// ------------------------------------------------ prep: sparsemax -> WpF (B-frag) + bias
__global__ __launch_bounds__(256) void k_prep_w(const float* __restrict__ fsl,
                                                const float* __restrict__ thr,
                                                const float* __restrict__ logt,
                                                unsigned short* __restrict__ WpF,
                                                float* __restrict__ bias) {
    int t = blockIdx.x * 256 + threadIdx.x;   // 32768 = 256 feats * 128 trees
    int i = t >> 7;     // feature (= k index)
    int n = t & 127;    // tree
    const float* zp = fsl + (i * 128 + n) * 6;

    float z[6], zs[6];
    #pragma unroll
    for (int d = 0; d < 6; ++d) { z[d] = zp[d]; zs[d] = z[d]; }
    #pragma unroll
    for (int a = 0; a < 5; ++a) {
        #pragma unroll
        for (int b = a + 1; b < 6; ++b) {
            float hi = fmaxf(zs[a], zs[b]);
            float lo = fminf(zs[a], zs[b]);
            zs[a] = hi; zs[b] = lo;
        }
    }
    float cs = 0.f, csel = 0.f;
    int   km = 1;
    #pragma unroll
    for (int k = 0; k < 6; ++k) {
        cs += zs[k];
        if (1.0f + (float)(k + 1) * zs[k] > cs) { km = k + 1; csel = cs; }
    }
    float tau = (csel - 1.0f) / (float)km;

    // fragment coords from k=i
    int kt = i >> 5, lq = (i >> 3) & 3, j = i & 7;
    #pragma unroll
    for (int d = 0; d < 6; ++d) {
        float invT = expf(-logt[n * 6 + d]);
        float sel  = fmaxf(z[d] - tau, 0.0f);
        float wv   = sel * 0.5f * invT;
        int col = n * 6 + d;
        int ct = col >> 4, cl = col & 15;
        int idx = ((ct * 8 + kt) * 64 + lq * 16 + cl) * 8 + j;
        WpF[idx] = bf16r(wv);
        if (i == 0) bias[col] = 0.5f - 0.5f * invT * thr[n * 6 + d];
    }
}

// ------------------------------------------------ prep: response -> respF (B-frag per tree)
__global__ __launch_bounds__(256) void k_prep_r(const float* __restrict__ resp,
                                                unsigned short* __restrict__ respF) {
    int t = blockIdx.x * 256 + threadIdx.x;   // 16384 = 128 n * 2 kt * 64 lanes
    int n  = t >> 7;
    int k2 = (t >> 6) & 1;
    int l  = t & 63;
    int u  = l & 15;
    int c0 = k2 * 32 + (l >> 4) * 8;
    const float* rp = resp + n * 1024 + u * 64 + c0;   // resp[n][u][c]
    float4 ra = *(const float4*)rp;
    float4 rb = *(const float4*)(rp + 4);
    u32 w0 = pack2(ra.x, ra.y);
    u32 w1 = pack2(ra.z, ra.w);
    u32 w2 = pack2(rb.x, rb.y);
    u32 w3 = pack2(rb.z, rb.w);
    int4 o; o.x = (int)w0; o.y = (int)w1; o.z = (int)w2; o.w = (int)w3;
    ((int4*)respF)[(n * 2 + k2) * 64 + l] = o;
}

// ------------------------------------------------ main fused kernel
__global__ __launch_bounds__(512) void k_main(const float* __restrict__ x,
                                              const unsigned short* __restrict__ WpF,
                                              const unsigned short* __restrict__ respF,
                                              const float* __restrict__ bias,
                                              float* __restrict__ out) {
    __shared__ char smemraw[49664];
    unsigned short* gl = (unsigned short*)smemraw;   // gates bf16 [32][GLD]
    float* lds2 = (float*)smemraw;                    // aliased reduce buffer

    int tid = threadIdx.x;
    int w  = tid >> 6;      // wave 0..7
    int l  = tid & 63;
    int cl = l & 15;
    int lq = l >> 4;
    int rowbase = blockIdx.x * 32;
    int ntbase  = w * 6;    // 6 col-tiles (96 cols) per wave

    f32x4 acc[6][2];
    #pragma unroll
    for (int j = 0; j < 6; ++j) {
        acc[j][0] = (f32x4){0.f, 0.f, 0.f, 0.f};
        acc[j][1] = (f32x4){0.f, 0.f, 0.f, 0.f};
    }

    const int4* wp4 = (const int4*)WpF;

    // -------- phase 1: gates GEMM (x hi/lo split, W bf16)
    for (int kt = 0; kt < 8; ++kt) {
        frag_u b[6];
        #pragma unroll
        for (int j = 0; j < 6; ++j)
            b[j].i4 = wp4[((ntbase + j) * 8 + kt) * 64 + l];

        #pragma unroll
        for (int rt = 0; rt < 2; ++rt) {
            const float* xp = x + (size_t)(rowbase + rt * 16 + cl) * 256 + kt * 32 + lq * 8;
            float4 xa = *(const float4*)xp;
            float4 xb = *(const float4*)(xp + 4);
            float xv[8] = {xa.x, xa.y, xa.z, xa.w, xb.x, xb.y, xb.z, xb.w};
            frag_u ah, al;
            ah.w[0] = pack2(xv[0], xv[1]);
            ah.w[1] = pack2(xv[2], xv[3]);
            ah.w[2] = pack2(xv[4], xv[5]);
            ah.w[3] = pack2(xv[6], xv[7]);
            float lo[8];
            #pragma unroll
            for (int p = 0; p < 4; ++p) {
                float f0 = __uint_as_float(ah.w[p] << 16);
                float f1 = __uint_as_float(ah.w[p] & 0xffff0000u);
                lo[p * 2]     = xv[p * 2]     - f0;
                lo[p * 2 + 1] = xv[p * 2 + 1] - f1;
            }
            al.w[0] = pack2(lo[0], lo[1]);
            al.w[1] = pack2(lo[2], lo[3]);
            al.w[2] = pack2(lo[4], lo[5]);
            al.w[3] = pack2(lo[6], lo[7]);
            #pragma unroll
            for (int j = 0; j < 6; ++j) {
                acc[j][rt] = mfma_bf16(ah.v, b[j].v, acc[j][rt]);
                acc[j][rt] = mfma_bf16(al.v, b[j].v, acc[j][rt]);
            }
        }
    }

    // -------- phase 1 epilogue: bias + clamp -> gates bf16 in LDS
    #pragma unroll
    for (int j = 0; j < 6; ++j) {
        int col = (ntbase + j) * 16 + cl;
        float bv = bias[col];
        #pragma unroll
        for (int rt = 0; rt < 2; ++rt) {
            #pragma unroll
            for (int r = 0; r < 4; ++r) {
                float g = acc[j][rt][r] + bv;
                g = fminf(fmaxf(g, 0.f), 1.f);
                int row = rt * 16 + lq * 4 + r;
                gl[row * GLD + col] = bf16r(g);
            }
        }
    }
    __syncthreads();

    // -------- phase 2: leaf-prob A-frags + response MFMA, 16 trees per wave
    f32x4 oacc0 = (f32x4){0.f, 0.f, 0.f, 0.f};
    f32x4 oacc1 = (f32x4){0.f, 0.f, 0.f, 0.f};
    const int4* rp4 = (const int4*)respF;
    int treebase = w * 16;

    #pragma unroll 2
    for (int t2 = 0; t2 < 16; ++t2) {
        int n = treebase + t2;
        frag_u rb0, rb1;
        rb0.i4 = rp4[(n * 2 + 0) * 64 + l];
        rb1.i4 = rp4[(n * 2 + 1) * 64 + l];
        #pragma unroll
        for (int rt = 0; rt < 2; ++rt) {
            int row = rt * 16 + cl;
            const u32* gp = (const u32*)((const char*)gl + row * GLROWB + n * 12);
            u32 d0 = gp[0], d1 = gp[1], d2 = gp[2];
            float g0 = __uint_as_float(d0 << 16), g1 = __uint_as_float(d0 & 0xffff0000u);
            float g2 = __uint_as_float(d1 << 16), g3 = __uint_as_float(d1 & 0xffff0000u);
            float g4 = __uint_as_float(d2 << 16), g5 = __uint_as_float(d2 & 0xffff0000u);
            float s0 = 1.f - g0, s1 = 1.f - g1, s2 = 1.f - g2;
            float s3 = 1.f - g3, s4 = 1.f - g4, s5 = 1.f - g5;
            float t01[4] = {g0 * g1, s0 * g1, g0 * s1, s0 * s1};
            float pa[8];
            #pragma unroll
            for (int ca = 0; ca < 8; ++ca)
                pa[ca] = t01[ca & 3] * ((ca & 4) ? s2 : g2);
            float f3 = (lq & 1) ? s3 : g3;
            float f4 = (lq & 2) ? s4 : g4;
            float m34 = f3 * f4;
            float pbl = m34 * g5;   // cb = lq      (bit5 = 0)
            float pbh = m34 * s5;   // cb = lq + 4  (bit5 = 1)
            frag_u fa1, fa2;
            #pragma unroll
            for (int p = 0; p < 4; ++p) {
                fa1.w[p] = pack2(pa[p * 2] * pbl, pa[p * 2 + 1] * pbl);
                fa2.w[p] = pack2(pa[p * 2] * pbh, pa[p * 2 + 1] * pbh);
            }
            if (rt == 0) {
                oacc0 = mfma_bf16(fa1.v, rb0.v, oacc0);
                oacc0 = mfma_bf16(fa2.v, rb1.v, oacc0);
            } else {
                oacc1 = mfma_bf16(fa1.v, rb0.v, oacc1);
                oacc1 = mfma_bf16(fa2.v, rb1.v, oacc1);
            }
        }
    }
    __syncthreads();   // gl dead; reuse as reduce buffer

    // -------- cross-wave reduce (trees were split across waves)
    #pragma unroll
    for (int r = 0; r < 4; ++r) {
        lds2[(w * 2 + 0) * 272 + (lq * 4 + r) * 17 + cl] = oacc0[r];
        lds2[(w * 2 + 1) * 272 + (lq * 4 + r) * 17 + cl] = oacc1[r];
    }
    __syncthreads();
    {
        int r = tid >> 4, u = tid & 15;     // 512 threads -> 32 rows x 16 u
        int rt = r >> 4, ri = r & 15;
        float s = 0.f;
        #pragma unroll
        for (int ww = 0; ww < 8; ++ww)
            s += lds2[(ww * 2 + rt) * 272 + ri * 17 + u];
        out[(size_t)(rowbase + r) * 16 + u] = s * (1.0f / 128.0f);
    }
}

// ------------------------------------------------ launch
extern "C" void kernel_launch(void* const* d_in, const int* in_sizes, int n_in,
                              void* d_out, int out_size, void* d_ws, size_t ws_size,
                              hipStream_t stream) {
    (void)in_sizes; (void)n_in; (void)out_size; (void)ws_size;
    const float* x    = (const float*)d_in[0];
    const float* fsl  = (const float*)d_in[1];
    const float* thr  = (const float*)d_in[2];
    const float* logt = (const float*)d_in[3];
    const float* resp = (const float*)d_in[4];

    char* ws = (char*)d_ws;
    unsigned short* WpF   = (unsigned short*)(ws + WPF_OFF);
    unsigned short* respF = (unsigned short*)(ws + RESPF_OFF);
    float*          bias  = (float*)(ws + BIAS_OFF);
    float* out = (float*)d_out;

    k_prep_w<<<128, 256, 0, stream>>>(fsl, thr, logt, WpF, bias);
    k_prep_r<<<64, 256, 0, stream>>>(resp, respF);
    k_main  <<<256, 512, 0, stream>>>(x, WpF, respF, bias, out);
}

// Round 3
// 25.784 us; speedup vs baseline: 4.8802x; 1.2727x over previous
//
#include <hip/hip_runtime.h>
#include <hip/hip_bf16.h>

// B=8192, F=256(K), N=128 trees, D=6, U=16, C=64
// cols = n*6+d  (768 total)

typedef float f32x4 __attribute__((ext_vector_type(4)));
typedef short s16x8 __attribute__((ext_vector_type(8)));
typedef unsigned int u32;

// ws layout (bytes):
//   WpF   bf16 [48ct][8kt][64lane][8]  @ 0        393216 B
//   respF bf16 [128n][2kt][64lane][8]  @ 393216   262144 B
//   bias  f32  [768]                   @ 655360     3072 B
#define WPF_OFF   0
#define RESPF_OFF 393216
#define BIAS_OFF  655360

#define GLD    776            // gates LDS row stride (bf16 elems), 768+8 pad
#define GLROWB (GLD * 2)      // 1552 bytes

__device__ inline unsigned short bf16r(float f) {
    union { __hip_bfloat16 b; unsigned short s; } u;
    u.b = __float2bfloat16(f);
    return u.s;
}

__device__ inline u32 pack2(float a, float b) {
    union { __hip_bfloat162 h; u32 u; } p;
    p.h = __float22bfloat162_rn(make_float2(a, b));
    return p.u;
}

union frag_u { u32 w[4]; s16x8 v; int4 i4; };

__device__ inline f32x4 mfma_bf16(s16x8 a, s16x8 b, f32x4 c) {
    return __builtin_amdgcn_mfma_f32_16x16x32_bf16(a, b, c, 0, 0, 0);
}

// ------------------------------------------------ merged prep kernel
// blocks 0..127   : sparsemax -> WpF (B-frag layout) + bias
// blocks 128..191 : response -> respF (B-frag per tree)
__global__ __launch_bounds__(256) void k_prep(const float* __restrict__ fsl,
                                              const float* __restrict__ thr,
                                              const float* __restrict__ logt,
                                              const float* __restrict__ resp,
                                              unsigned short* __restrict__ WpF,
                                              unsigned short* __restrict__ respF,
                                              float* __restrict__ bias) {
    int bb  = blockIdx.x;
    int tid = threadIdx.x;
    if (bb < 128) {
        int t = bb * 256 + tid;   // 32768 = 256 feats * 128 trees
        int i = t >> 7;     // feature (= k index)
        int n = t & 127;    // tree
        const float* zp = fsl + (i * 128 + n) * 6;

        float z[6], zs[6];
        #pragma unroll
        for (int d = 0; d < 6; ++d) { z[d] = zp[d]; zs[d] = z[d]; }
        #pragma unroll
        for (int a = 0; a < 5; ++a) {
            #pragma unroll
            for (int b = a + 1; b < 6; ++b) {
                float hi = fmaxf(zs[a], zs[b]);
                float lo = fminf(zs[a], zs[b]);
                zs[a] = hi; zs[b] = lo;
            }
        }
        float cs = 0.f, csel = 0.f;
        int   km = 1;
        #pragma unroll
        for (int k = 0; k < 6; ++k) {
            cs += zs[k];
            if (1.0f + (float)(k + 1) * zs[k] > cs) { km = k + 1; csel = cs; }
        }
        float tau = (csel - 1.0f) / (float)km;

        int kt = i >> 5, lq = (i >> 3) & 3, j = i & 7;
        #pragma unroll
        for (int d = 0; d < 6; ++d) {
            float invT = expf(-logt[n * 6 + d]);
            float sel  = fmaxf(z[d] - tau, 0.0f);
            float wv   = sel * 0.5f * invT;
            int col = n * 6 + d;
            int ct = col >> 4, cl = col & 15;
            int idx = ((ct * 8 + kt) * 64 + lq * 16 + cl) * 8 + j;
            WpF[idx] = bf16r(wv);
            if (i == 0) bias[col] = 0.5f - 0.5f * invT * thr[n * 6 + d];
        }
    } else {
        int t = (bb - 128) * 256 + tid;   // 16384 = 128 n * 2 kt * 64 lanes
        int n  = t >> 7;
        int k2 = (t >> 6) & 1;
        int l  = t & 63;
        int u  = l & 15;
        int c0 = k2 * 32 + (l >> 4) * 8;
        const float* rp = resp + n * 1024 + u * 64 + c0;   // resp[n][u][c]
        float4 ra = *(const float4*)rp;
        float4 rb = *(const float4*)(rp + 4);
        int4 o;
        o.x = (int)pack2(ra.x, ra.y);
        o.y = (int)pack2(ra.z, ra.w);
        o.z = (int)pack2(rb.x, rb.y);
        o.w = (int)pack2(rb.z, rb.w);
        ((int4*)respF)[(n * 2 + k2) * 64 + l] = o;
    }
}

// ------------------------------------------------ main fused kernel
// 1024 threads = 16 waves; BM=32 rows/block; grid 256.
// phase 0: stage x -> hi/lo bf16 A-frags in LDS (32 KB)
// phase 1: gates GEMM, wave w owns 3 col-tiles (48 cols)
// phase 2: leaf probs + response MFMA, wave w owns 8 trees
__global__ __launch_bounds__(1024, 4) void k_main(const float* __restrict__ x,
                                                  const unsigned short* __restrict__ WpF,
                                                  const unsigned short* __restrict__ respF,
                                                  const float* __restrict__ bias,
                                                  float* __restrict__ out) {
    __shared__ char smemraw[49664];
    unsigned short* gl = (unsigned short*)smemraw;   // gates bf16 [32][GLD]
    float* lds2 = (float*)smemraw;                    // aliased reduce buffer
    const int4* xf = (const int4*)smemraw;            // aliased x A-frags

    int tid = threadIdx.x;
    int w  = tid >> 6;      // wave 0..15
    int l  = tid & 63;
    int cl = l & 15;
    int lq = l >> 4;
    int rowbase = blockIdx.x * 32;
    int ntbase  = w * 3;    // 3 col-tiles (48 cols) per wave

    // -------- phase 0: stage x as hi/lo A-frags
    {
        int row = tid & 31;          // 0..31
        int k8  = tid >> 5;          // 0..31 (8-float chunk)
        const float* xp = x + (size_t)(rowbase + row) * 256 + k8 * 8;
        float4 xa = *(const float4*)xp;
        float4 xb = *(const float4*)(xp + 4);
        float xv[8] = {xa.x, xa.y, xa.z, xa.w, xb.x, xb.y, xb.z, xb.w};
        int4 hi4, lo4;
        u32 hw[4];
        float lo[8];
        #pragma unroll
        for (int p = 0; p < 4; ++p) {
            hw[p] = pack2(xv[p * 2], xv[p * 2 + 1]);
            float f0 = __uint_as_float(hw[p] << 16);
            float f1 = __uint_as_float(hw[p] & 0xffff0000u);
            lo[p * 2]     = xv[p * 2]     - f0;
            lo[p * 2 + 1] = xv[p * 2 + 1] - f1;
        }
        hi4.x = (int)hw[0]; hi4.y = (int)hw[1]; hi4.z = (int)hw[2]; hi4.w = (int)hw[3];
        lo4.x = (int)pack2(lo[0], lo[1]);
        lo4.y = (int)pack2(lo[2], lo[3]);
        lo4.z = (int)pack2(lo[4], lo[5]);
        lo4.w = (int)pack2(lo[6], lo[7]);
        int rt = row >> 4, rl = row & 15, kt = k8 >> 2, klq = k8 & 3;
        char* basep = smemraw + (size_t)((rt * 8 + kt) * 2) * 1024 + (klq * 16 + rl) * 16;
        *(int4*)basep = hi4;
        *(int4*)(basep + 1024) = lo4;
    }
    __syncthreads();

    // -------- phase 1: gates GEMM (x hi/lo from LDS, W bf16 from global)
    f32x4 acc[3][2];
    #pragma unroll
    for (int j = 0; j < 3; ++j) {
        acc[j][0] = (f32x4){0.f, 0.f, 0.f, 0.f};
        acc[j][1] = (f32x4){0.f, 0.f, 0.f, 0.f};
    }
    const int4* wp4 = (const int4*)WpF;

    #pragma unroll
    for (int kt = 0; kt < 8; ++kt) {
        frag_u b[3];
        #pragma unroll
        for (int j = 0; j < 3; ++j)
            b[j].i4 = wp4[((ntbase + j) * 8 + kt) * 64 + l];
        #pragma unroll
        for (int rt = 0; rt < 2; ++rt) {
            frag_u ah, al;
            ah.i4 = xf[((rt * 8 + kt) * 2 + 0) * 64 + l];
            al.i4 = xf[((rt * 8 + kt) * 2 + 1) * 64 + l];
            #pragma unroll
            for (int j = 0; j < 3; ++j) {
                acc[j][rt] = mfma_bf16(ah.v, b[j].v, acc[j][rt]);
                acc[j][rt] = mfma_bf16(al.v, b[j].v, acc[j][rt]);
            }
        }
    }
    __syncthreads();   // xfrags dead; smem becomes gates

    // -------- phase 1 epilogue: bias + clamp -> gates bf16 in LDS
    #pragma unroll
    for (int j = 0; j < 3; ++j) {
        int col = (ntbase + j) * 16 + cl;
        float bv = bias[col];
        #pragma unroll
        for (int rt = 0; rt < 2; ++rt) {
            #pragma unroll
            for (int r = 0; r < 4; ++r) {
                float g = acc[j][rt][r] + bv;
                g = fminf(fmaxf(g, 0.f), 1.f);
                int row = rt * 16 + lq * 4 + r;
                gl[row * GLD + col] = bf16r(g);
            }
        }
    }
    __syncthreads();

    // -------- phase 2: leaf-prob A-frags + response MFMA, 8 trees per wave
    f32x4 oacc0 = (f32x4){0.f, 0.f, 0.f, 0.f};
    f32x4 oacc1 = (f32x4){0.f, 0.f, 0.f, 0.f};
    const int4* rp4 = (const int4*)respF;
    int treebase = w * 8;

    #pragma unroll 2
    for (int t2 = 0; t2 < 8; ++t2) {
        int n = treebase + t2;
        frag_u rb0, rb1;
        rb0.i4 = rp4[(n * 2 + 0) * 64 + l];
        rb1.i4 = rp4[(n * 2 + 1) * 64 + l];
        #pragma unroll
        for (int rt = 0; rt < 2; ++rt) {
            int row = rt * 16 + cl;
            const u32* gp = (const u32*)((const char*)gl + row * GLROWB + n * 12);
            u32 d0 = gp[0], d1 = gp[1], d2 = gp[2];
            float g0 = __uint_as_float(d0 << 16), g1 = __uint_as_float(d0 & 0xffff0000u);
            float g2 = __uint_as_float(d1 << 16), g3 = __uint_as_float(d1 & 0xffff0000u);
            float g4 = __uint_as_float(d2 << 16), g5 = __uint_as_float(d2 & 0xffff0000u);
            float s0 = 1.f - g0, s1 = 1.f - g1, s2 = 1.f - g2;
            float s3 = 1.f - g3, s4 = 1.f - g4, s5 = 1.f - g5;
            float t01[4] = {g0 * g1, s0 * g1, g0 * s1, s0 * s1};
            float pa[8];
            #pragma unroll
            for (int ca = 0; ca < 8; ++ca)
                pa[ca] = t01[ca & 3] * ((ca & 4) ? s2 : g2);
            float f3 = (lq & 1) ? s3 : g3;
            float f4 = (lq & 2) ? s4 : g4;
            float m34 = f3 * f4;
            float pbl = m34 * g5;   // cb = lq      (bit5 = 0)
            float pbh = m34 * s5;   // cb = lq + 4  (bit5 = 1)
            frag_u fa1, fa2;
            #pragma unroll
            for (int p = 0; p < 4; ++p) {
                fa1.w[p] = pack2(pa[p * 2] * pbl, pa[p * 2 + 1] * pbl);
                fa2.w[p] = pack2(pa[p * 2] * pbh, pa[p * 2 + 1] * pbh);
            }
            if (rt == 0) {
                oacc0 = mfma_bf16(fa1.v, rb0.v, oacc0);
                oacc0 = mfma_bf16(fa2.v, rb1.v, oacc0);
            } else {
                oacc1 = mfma_bf16(fa1.v, rb0.v, oacc1);
                oacc1 = mfma_bf16(fa2.v, rb1.v, oacc1);
            }
        }
    }
    __syncthreads();   // gates dead; smem becomes reduce buffer

    // -------- cross-wave reduce (16 waves each hold partial over 8 trees)
    #pragma unroll
    for (int r = 0; r < 4; ++r) {
        lds2[(w * 2 + 0) * 272 + (lq * 4 + r) * 17 + cl] = oacc0[r];
        lds2[(w * 2 + 1) * 272 + (lq * 4 + r) * 17 + cl] = oacc1[r];
    }
    __syncthreads();
    if (tid < 512) {
        int r = tid >> 4, u = tid & 15;     // 32 rows x 16 u
        int rt = r >> 4, ri = r & 15;
        float s = 0.f;
        #pragma unroll
        for (int ww = 0; ww < 16; ++ww)
            s += lds2[(ww * 2 + rt) * 272 + ri * 17 + u];
        out[(size_t)(rowbase + r) * 16 + u] = s * (1.0f / 128.0f);
    }
}

// ------------------------------------------------ launch
extern "C" void kernel_launch(void* const* d_in, const int* in_sizes, int n_in,
                              void* d_out, int out_size, void* d_ws, size_t ws_size,
                              hipStream_t stream) {
    (void)in_sizes; (void)n_in; (void)out_size; (void)ws_size;
    const float* x    = (const float*)d_in[0];
    const float* fsl  = (const float*)d_in[1];
    const float* thr  = (const float*)d_in[2];
    const float* logt = (const float*)d_in[3];
    const float* resp = (const float*)d_in[4];

    char* ws = (char*)d_ws;
    unsigned short* WpF   = (unsigned short*)(ws + WPF_OFF);
    unsigned short* respF = (unsigned short*)(ws + RESPF_OFF);
    float*          bias  = (float*)(ws + BIAS_OFF);
    float* out = (float*)d_out;

    k_prep<<<192, 256, 0, stream>>>(fsl, thr, logt, resp, WpF, respF, bias);
    k_main<<<256, 1024, 0, stream>>>(x, WpF, respF, bias, out);
}

// Round 4
// 21.721 us; speedup vs baseline: 5.7930x; 1.1870x over previous
//
#include <hip/hip_runtime.h>
#include <hip/hip_bf16.h>

// B=8192, F=256(K), N=128 trees, D=6, U=16, C=64
// cols = n*6+d  (768 total)

typedef float f32x4 __attribute__((ext_vector_type(4)));
typedef unsigned int u32;
typedef _Float16 h16;
typedef _Float16 h16x2 __attribute__((ext_vector_type(2)));
typedef _Float16 h16x8 __attribute__((ext_vector_type(8)));

// ws layout (bytes):
//   WpF   fp16 [48ct][8kt][64lane][8]  @ 0        393216 B
//   respF fp16 [128n][2kt][64lane][8]  @ 393216   262144 B
//   bias  f32  [768]                   @ 655360     3072 B
#define WPF_OFF   0
#define RESPF_OFF 393216
#define BIAS_OFF  655360

#define GLD    776            // gates LDS row stride (fp16 elems), 768+8 pad
#define GLROWB (GLD * 2)      // 1552 bytes

union h2u { h16x2 h; u32 u; };
union hbits { h16 h; unsigned short s; };
union fragh { u32 w[4]; h16x8 v; int4 i4; h16x2 h2[4]; };

__device__ inline unsigned short h16r(float f) {
    hbits t; t.h = (h16)f; return t.s;
}
__device__ inline u32 packh2(float a, float b) {
    h2u t; t.h[0] = (h16)a; t.h[1] = (h16)b; return t.u;
}

__device__ inline f32x4 mfma_f16(h16x8 a, h16x8 b, f32x4 c) {
    return __builtin_amdgcn_mfma_f32_16x16x32_f16(a, b, c, 0, 0, 0);
}

// ------------------------------------------------ merged prep kernel
// blocks 0..127   : sparsemax -> WpF (B-frag layout, fp16) + bias
//                   block = 8 features x 32 trees (kt,lq uniform per block)
// blocks 128..191 : response -> respF (B-frag per tree, fp16)
__global__ __launch_bounds__(256) void k_prep(const float* __restrict__ fsl,
                                              const float* __restrict__ thr,
                                              const float* __restrict__ logt,
                                              const float* __restrict__ resp,
                                              unsigned short* __restrict__ WpF,
                                              unsigned short* __restrict__ respF,
                                              float* __restrict__ bias) {
    int bb  = blockIdx.x;
    int tid = threadIdx.x;
    if (bb < 128) {
        __shared__ unsigned short sm[8][192];
        int ib = (bb & 31) * 8;    // feature base (32 iblocks)
        int nb = (bb >> 5) * 32;   // tree base    (4 nblocks)
        int il = tid >> 5;         // 0..7 local feature
        int nl = tid & 31;         // 0..31 local tree
        int i = ib + il;
        int n = nb + nl;
        const float* zp = fsl + (i * 128 + n) * 6;

        float z[6], zs[6];
        #pragma unroll
        for (int d = 0; d < 6; ++d) { z[d] = zp[d]; zs[d] = z[d]; }
        #pragma unroll
        for (int a = 0; a < 5; ++a) {
            #pragma unroll
            for (int b = a + 1; b < 6; ++b) {
                float hi = fmaxf(zs[a], zs[b]);
                float lo = fminf(zs[a], zs[b]);
                zs[a] = hi; zs[b] = lo;
            }
        }
        float cs = 0.f, csel = 0.f;
        int   km = 1;
        #pragma unroll
        for (int k = 0; k < 6; ++k) {
            cs += zs[k];
            if (1.0f + (float)(k + 1) * zs[k] > cs) { km = k + 1; csel = cs; }
        }
        float tau = (csel - 1.0f) / (float)km;

        #pragma unroll
        for (int d = 0; d < 6; ++d) {
            float invT = expf(-logt[n * 6 + d]);
            float sel  = fmaxf(z[d] - tau, 0.0f);
            float wv   = sel * 0.5f * invT;
            sm[il][nl * 6 + d] = h16r(wv);
            if (i == 0) bias[n * 6 + d] = 0.5f - 0.5f * invT * thr[n * 6 + d];
        }
        __syncthreads();

        if (tid < 192) {
            int ct  = (nb * 6) / 16 + (tid >> 4);   // nb*6 is a multiple of 192
            int clm = tid & 15;
            int kt  = ib >> 5;
            int lq  = (ib >> 3) & 3;
            union { unsigned short s[8]; int4 i4; } o;
            #pragma unroll
            for (int j = 0; j < 8; ++j) o.s[j] = sm[j][tid];
            *(int4*)(WpF + (size_t)(((ct * 8 + kt) * 64 + lq * 16 + clm) * 8)) = o.i4;
        }
    } else {
        int t = (bb - 128) * 256 + tid;   // 16384 = 128 n * 2 kt * 64 lanes
        int n  = t >> 7;
        int k2 = (t >> 6) & 1;
        int l  = t & 63;
        int u  = l & 15;
        int c0 = k2 * 32 + (l >> 4) * 8;
        const float* rp = resp + n * 1024 + u * 64 + c0;   // resp[n][u][c]
        float4 ra = *(const float4*)rp;
        float4 rb = *(const float4*)(rp + 4);
        int4 o;
        o.x = (int)packh2(ra.x, ra.y);
        o.y = (int)packh2(ra.z, ra.w);
        o.z = (int)packh2(rb.x, rb.y);
        o.w = (int)packh2(rb.z, rb.w);
        ((int4*)respF)[(n * 2 + k2) * 64 + l] = o;
    }
}

// ------------------------------------------------ main fused kernel
// 1024 threads = 16 waves; BM=32 rows/block; grid 256.
// phase 0: stage x -> fp16 A-frags in LDS (16 KB), kt-XOR swizzled
// phase 1: gates GEMM (fp16 single-pass), wave w owns 3 col-tiles
// phase 2: packed-fp16 leaf probs + response MFMA, wave w owns 8 trees
__global__ __launch_bounds__(1024, 4) void k_main(const float* __restrict__ x,
                                                  const unsigned short* __restrict__ WpF,
                                                  const unsigned short* __restrict__ respF,
                                                  const float* __restrict__ bias,
                                                  float* __restrict__ out) {
    __shared__ char smemraw[49664];
    unsigned short* gl = (unsigned short*)smemraw;   // gates fp16 [32][GLD]
    float* lds2 = (float*)smemraw;                    // aliased reduce buffer
    const int4* xf = (const int4*)smemraw;            // aliased x A-frags

    int tid = threadIdx.x;
    int w  = tid >> 6;      // wave 0..15
    int l  = tid & 63;
    int cl = l & 15;
    int lq = l >> 4;
    int rowbase = blockIdx.x * 32;
    int ntbase  = w * 3;    // 3 col-tiles (48 cols) per wave

    // -------- phase 0: stage x as fp16 A-frags (coalesced reads, XOR-swizzled writes)
    {
        int k8  = tid & 31;          // 8-float chunk (fast: coalesced global)
        int row = tid >> 5;          // 0..31
        const float* xp = x + (size_t)(rowbase + row) * 256 + k8 * 8;
        float4 xa = *(const float4*)(xp);
        float4 xb = *(const float4*)(xp + 4);
        int4 p;
        p.x = (int)packh2(xa.x, xa.y);
        p.y = (int)packh2(xa.z, xa.w);
        p.z = (int)packh2(xb.x, xb.y);
        p.w = (int)packh2(xb.z, xb.w);
        int rt = row >> 4, rl = row & 15, kt = k8 >> 2, klq = k8 & 3;
        // element (klq*16+rl) of frag (rt,kt), position XOR-swizzled by kt
        char* basep = smemraw + (size_t)(rt * 8 + kt) * 1024
                              + (size_t)(((klq * 16 + rl) ^ kt) * 16);
        *(int4*)basep = p;
    }
    __syncthreads();

    // -------- phase 1: gates GEMM (x fp16 from LDS, W fp16 from global)
    f32x4 acc[3][2];
    #pragma unroll
    for (int j = 0; j < 3; ++j) {
        acc[j][0] = (f32x4){0.f, 0.f, 0.f, 0.f};
        acc[j][1] = (f32x4){0.f, 0.f, 0.f, 0.f};
    }
    const int4* wp4 = (const int4*)WpF;

    #pragma unroll
    for (int kt = 0; kt < 8; ++kt) {
        fragh b[3];
        #pragma unroll
        for (int j = 0; j < 3; ++j)
            b[j].i4 = wp4[((ntbase + j) * 8 + kt) * 64 + l];
        #pragma unroll
        for (int rt = 0; rt < 2; ++rt) {
            fragh ah;
            ah.i4 = xf[(rt * 8 + kt) * 64 + (l ^ kt)];
            #pragma unroll
            for (int j = 0; j < 3; ++j)
                acc[j][rt] = mfma_f16(ah.v, b[j].v, acc[j][rt]);
        }
    }
    __syncthreads();   // xfrags dead; smem becomes gates

    // -------- phase 1 epilogue: bias + clamp -> gates fp16 in LDS
    #pragma unroll
    for (int j = 0; j < 3; ++j) {
        int col = (ntbase + j) * 16 + cl;
        float bv = bias[col];
        #pragma unroll
        for (int rt = 0; rt < 2; ++rt) {
            #pragma unroll
            for (int r = 0; r < 4; ++r) {
                float g = acc[j][rt][r] + bv;
                g = fminf(fmaxf(g, 0.f), 1.f);
                int row = rt * 16 + lq * 4 + r;
                gl[row * GLD + col] = h16r(g);
            }
        }
    }
    __syncthreads();

    // -------- phase 2: packed-fp16 leaf probs + response MFMA, 8 trees/wave
    f32x4 oacc0 = (f32x4){0.f, 0.f, 0.f, 0.f};
    f32x4 oacc1 = (f32x4){0.f, 0.f, 0.f, 0.f};
    const int4* rp4 = (const int4*)respF;
    int treebase = w * 8;
    const h16x2 onev = (h16x2){(h16)1.0f, (h16)1.0f};

    #pragma unroll 2
    for (int t2 = 0; t2 < 8; ++t2) {
        int n = treebase + t2;
        fragh rb0, rb1;
        rb0.i4 = rp4[(n * 2 + 0) * 64 + l];
        rb1.i4 = rp4[(n * 2 + 1) * 64 + l];
        #pragma unroll
        for (int rt = 0; rt < 2; ++rt) {
            int row = rt * 16 + cl;
            const u32* gp = (const u32*)((const char*)gl + row * GLROWB + n * 12);
            h2u g01u, g23u, g45u;
            g01u.u = gp[0]; g23u.u = gp[1]; g45u.u = gp[2];
            h16x2 g01 = g01u.h, g23 = g23u.h, g45 = g45u.h;
            h16x2 s01 = onev - g01;
            h16x2 s23 = onev - g23;
            h16x2 s45 = onev - g45;
            // pa pairs (leaf bits 0..2), packed
            h16x2 gs0  = __builtin_shufflevector(g01, s01, 0, 2);   // (g0,s0)
            h16x2 b1g  = __builtin_shufflevector(g01, g01, 1, 1);   // (g1,g1)
            h16x2 b1s  = __builtin_shufflevector(s01, s01, 1, 1);   // (s1,s1)
            h16x2 t01a = gs0 * b1g;    // (pa0', pa1')
            h16x2 t01b = gs0 * b1s;    // (pa2', pa3')
            h16x2 g2b  = __builtin_shufflevector(g23, g23, 0, 0);
            h16x2 s2b  = __builtin_shufflevector(s23, s23, 0, 0);
            h16x2 pa01 = t01a * g2b;
            h16x2 pa23 = t01b * g2b;
            h16x2 pa45 = t01a * s2b;
            h16x2 pa67 = t01b * s2b;
            // pb scalars (leaf bits 3..5; cb = lq / lq+4)
            h16 f3  = (lq & 1) ? s23[1] : g23[1];
            h16 f4  = (lq & 2) ? s45[0] : g45[0];
            h16 m34 = f3 * f4;
            h16 pbl = m34 * g45[1];    // bit5 = 0
            h16 pbh = m34 * s45[1];    // bit5 = 1
            h16x2 pblb = (h16x2){pbl, pbl};
            h16x2 pbhb = (h16x2){pbh, pbh};
            fragh fa1, fa2;
            fa1.h2[0] = pa01 * pblb; fa1.h2[1] = pa23 * pblb;
            fa1.h2[2] = pa45 * pblb; fa1.h2[3] = pa67 * pblb;
            fa2.h2[0] = pa01 * pbhb; fa2.h2[1] = pa23 * pbhb;
            fa2.h2[2] = pa45 * pbhb; fa2.h2[3] = pa67 * pbhb;
            if (rt == 0) {
                oacc0 = mfma_f16(fa1.v, rb0.v, oacc0);
                oacc0 = mfma_f16(fa2.v, rb1.v, oacc0);
            } else {
                oacc1 = mfma_f16(fa1.v, rb0.v, oacc1);
                oacc1 = mfma_f16(fa2.v, rb1.v, oacc1);
            }
        }
    }
    __syncthreads();   // gates dead; smem becomes reduce buffer

    // -------- cross-wave reduce (16 waves each hold partial over 8 trees)
    #pragma unroll
    for (int r = 0; r < 4; ++r) {
        lds2[(w * 2 + 0) * 272 + (lq * 4 + r) * 17 + cl] = oacc0[r];
        lds2[(w * 2 + 1) * 272 + (lq * 4 + r) * 17 + cl] = oacc1[r];
    }
    __syncthreads();
    if (tid < 512) {
        int r = tid >> 4, u = tid & 15;     // 32 rows x 16 u
        int rt = r >> 4, ri = r & 15;
        float s = 0.f;
        #pragma unroll
        for (int ww = 0; ww < 16; ++ww)
            s += lds2[(ww * 2 + rt) * 272 + ri * 17 + u];
        out[(size_t)(rowbase + r) * 16 + u] = s * (1.0f / 128.0f);
    }
}

// ------------------------------------------------ launch
extern "C" void kernel_launch(void* const* d_in, const int* in_sizes, int n_in,
                              void* d_out, int out_size, void* d_ws, size_t ws_size,
                              hipStream_t stream) {
    (void)in_sizes; (void)n_in; (void)out_size; (void)ws_size;
    const float* x    = (const float*)d_in[0];
    const float* fsl  = (const float*)d_in[1];
    const float* thr  = (const float*)d_in[2];
    const float* logt = (const float*)d_in[3];
    const float* resp = (const float*)d_in[4];

    char* ws = (char*)d_ws;
    unsigned short* WpF   = (unsigned short*)(ws + WPF_OFF);
    unsigned short* respF = (unsigned short*)(ws + RESPF_OFF);
    float*          bias  = (float*)(ws + BIAS_OFF);
    float* out = (float*)d_out;

    k_prep<<<192, 256, 0, stream>>>(fsl, thr, logt, resp, WpF, respF, bias);
    k_main<<<256, 1024, 0, stream>>>(x, WpF, respF, bias, out);
}